// Round 1
// baseline (356.500 us; speedup 1.0000x reference)
//
#include <hip/hip_runtime.h>
#include <hip/hip_bf16.h>
#include <math.h>

typedef __attribute__((ext_vector_type(4))) float f32x4;
typedef __attribute__((ext_vector_type(8))) short bf16x8;
typedef __attribute__((ext_vector_type(8))) unsigned short ushort8;

#define N_ROWS 8192
#define D 256

__device__ __forceinline__ unsigned short f2bf(float f) {
    unsigned int u = __float_as_uint(f);
    unsigned int r = u + 0x7FFFu + ((u >> 16) & 1u);
    return (unsigned short)(r >> 16);
}

__device__ __forceinline__ float breduce_sum256(float v, float* sb) {
#pragma unroll
    for (int off = 32; off; off >>= 1) v += __shfl_down(v, off);
    int wid = threadIdx.x >> 6;
    __syncthreads();
    if ((threadIdx.x & 63) == 0) sb[wid] = v;
    __syncthreads();
    return sb[0] + sb[1] + sb[2] + sb[3];
}

// K1: logx = logmap0(x), written to L (d_out used as scratch). col0 = 0.
__global__ void k_logmap0(const float* __restrict__ x, float* __restrict__ L) {
    __shared__ float sb[4];
    int row = blockIdx.x, t = threadIdx.x;
    float xv = x[(size_t)row * D + t];
    float yv = (t >= 1) ? xv : 0.f;
    float ss = breduce_sum256(yv * yv, sb);
    float ynorm = fmaxf(sqrtf(ss), 1e-15f);
    float x0 = x[(size_t)row * D];            // broadcast
    float th = fmaxf(x0, 1.f + 1e-7f);
    float al = acoshf(th);
    L[(size_t)row * D + t] = (t >= 1) ? (al * yv / ynorm) : 0.f;
}

// K2: M2[k][j] = sum_m W_gcn[k][m] * W_att[m+1][j]   (255 x 256)
__global__ void k_M2(const float* __restrict__ Wg, const float* __restrict__ Wa,
                     float* __restrict__ M2) {
    int k = blockIdx.x, t = threadIdx.x;
    float acc = 0.f;
#pragma unroll 8
    for (int m = 0; m < 255; ++m)
        acc += Wg[k * 255 + m] * Wa[(m + 1) * 256 + t];
    M2[k * 256 + t] = acc;
}

// K3: h[i][j] = sum_k L[i][k+1] * M2[k][j]
__global__ void k_h(const float* __restrict__ L, const float* __restrict__ M2,
                    float* __restrict__ h) {
    __shared__ float Ls[8][256];
    int i0 = blockIdx.x * 8, t = threadIdx.x;
    for (int r = 0; r < 8; ++r) Ls[r][t] = L[(size_t)(i0 + r) * D + t];
    __syncthreads();
    float acc[8] = {0.f, 0.f, 0.f, 0.f, 0.f, 0.f, 0.f, 0.f};
#pragma unroll 4
    for (int k = 0; k < 255; ++k) {
        float m2 = M2[k * 256 + t];
#pragma unroll
        for (int r = 0; r < 8; ++r) acc[r] += Ls[r][k + 1] * m2;
    }
    for (int r = 0; r < 8; ++r) h[(size_t)(i0 + r) * D + t] = acc[r];
}

// K4: c[j] = h[j,:] . a_att[256:512]
__global__ void k_cvec(const float* __restrict__ h, const float* __restrict__ aatt,
                       float* __restrict__ cvec) {
    __shared__ float sb[4];
    int row = blockIdx.x, t = threadIdx.x;
    float v = h[(size_t)row * D + t] * aatt[256 + t];
    float s = breduce_sum256(v, sb);
    if (t == 0) cvec[row] = s;
}

// K4b: global max of cvec
__global__ void k_max(const float* __restrict__ cvec, float* __restrict__ Mval) {
    __shared__ float sb[4];
    int t = threadIdx.x;
    float m = -3.4e38f;
    for (int i = t; i < N_ROWS; i += 256) m = fmaxf(m, cvec[i]);
#pragma unroll
    for (int off = 32; off; off >>= 1) m = fmaxf(m, __shfl_down(m, off));
    if ((t & 63) == 0) sb[t >> 6] = m;
    __syncthreads();
    if (t == 0) Mval[0] = fmaxf(fmaxf(sb[0], sb[1]), fmaxf(sb[2], sb[3]));
}

// K4c: wexp[j] = exp(c[j] - M)
__global__ void k_wexp(const float* __restrict__ cvec, const float* __restrict__ Mval,
                       float* __restrict__ wexp) {
    int i = blockIdx.x * 256 + threadIdx.x;
    if (i < N_ROWS) wexp[i] = expf(cvec[i] - Mval[0]);
}

// K5: GT[c][j] = bf16( wexp[j] * h[j][c] )   (256 x 8192, transposed store)
__global__ void k_makeGT(const float* __restrict__ h, const float* __restrict__ wexp,
                         unsigned short* __restrict__ GT) {
    __shared__ unsigned short tile[64][72];
    int J0 = blockIdx.x * 64, C0 = blockIdx.y * 64;
    int t = threadIdx.x;
    int cc = t & 63, r4 = t >> 6;
#pragma unroll
    for (int s = 0; s < 16; ++s) {
        int jr = r4 + s * 4;
        float w = wexp[J0 + jr];
        float v = h[(size_t)(J0 + jr) * D + C0 + cc] * w;
        tile[jr][cc] = f2bf(v);
    }
    __syncthreads();
#pragma unroll
    for (int s = 0; s < 16; ++s) {
        int cr = r4 + s * 4;
        GT[(size_t)(C0 + cr) * N_ROWS + J0 + cc] = tile[cc][cr];
    }
}

// K6: main masked GEMM.  hp_raw = adjf @ G   (8192x256), rowsum = adjf @ wexp
// Block: 256 thr (4 waves), BM=32 rows, BN=256 (full), BK=64.
__global__ void __launch_bounds__(256) k_attgemm(const int* __restrict__ adj,
                                                 const unsigned short* __restrict__ GT,
                                                 const float* __restrict__ wexp,
                                                 float* __restrict__ out,
                                                 float* __restrict__ rowsum) {
    __shared__ unsigned short As[32][64];    // [row][k] bf16
    __shared__ unsigned short Bs[256][64];   // [col][k] bf16 (B^T layout)
    __shared__ float rsred[32][8];
    int tid = threadIdx.x;
    int i0 = blockIdx.x * 32;
    int w = tid >> 6, l = tid & 63;
    int ar = tid >> 3, acs = tid & 7;        // A-stage: row, 8-int segment
    int bc = tid >> 3, bseg = tid & 7;       // B-stage: base col-row, 16B segment
    const int lr = l & 15, lk = (l >> 4) * 8;

    f32x4 zero4 = {0.f, 0.f, 0.f, 0.f};
    f32x4 acc[2][4];
#pragma unroll
    for (int m = 0; m < 2; ++m)
#pragma unroll
        for (int n = 0; n < 4; ++n) acc[m][n] = zero4;
    float rs = 0.f;

    for (int kt = 0; kt < N_ROWS / 64; ++kt) {
        int k0 = kt * 64;
        __syncthreads();
        // ---- stage A (adj -> bf16 0/1) + rowsum partials
        {
            const int4* ap = (const int4*)(adj + (size_t)(i0 + ar) * N_ROWS + k0 + acs * 8);
            int4 a0 = ap[0], a1 = ap[1];
            const float* wp = wexp + k0 + acs * 8;
            int av[8] = {a0.x, a0.y, a0.z, a0.w, a1.x, a1.y, a1.z, a1.w};
            ushort8 apk;
#pragma unroll
            for (int j = 0; j < 8; ++j) {
                apk[j] = av[j] ? (unsigned short)0x3F80 : (unsigned short)0;
                rs += av[j] ? wp[j] : 0.f;
            }
            *(ushort8*)(&As[ar][acs * 8]) = apk;
        }
        // ---- stage B (copy GT rows)
#pragma unroll
        for (int s = 0; s < 8; ++s) {
            int c = bc + s * 32;
            int4 bv = *(const int4*)(GT + (size_t)c * N_ROWS + k0 + bseg * 8);
            *(int4*)(&Bs[c][bseg * 8]) = bv;
        }
        __syncthreads();
        // ---- MFMA
        bf16x8 af[2][2], bfr[4][2];
#pragma unroll
        for (int m = 0; m < 2; ++m)
#pragma unroll
            for (int ks = 0; ks < 2; ++ks)
                af[m][ks] = *(const bf16x8*)(&As[m * 16 + lr][ks * 32 + lk]);
#pragma unroll
        for (int n = 0; n < 4; ++n)
#pragma unroll
            for (int ks = 0; ks < 2; ++ks)
                bfr[n][ks] = *(const bf16x8*)(&Bs[w * 64 + n * 16 + lr][ks * 32 + lk]);
#pragma unroll
        for (int m = 0; m < 2; ++m)
#pragma unroll
            for (int n = 0; n < 4; ++n) {
                acc[m][n] = __builtin_amdgcn_mfma_f32_16x16x32_bf16(af[m][0], bfr[n][0], acc[m][n], 0, 0, 0);
                acc[m][n] = __builtin_amdgcn_mfma_f32_16x16x32_bf16(af[m][1], bfr[n][1], acc[m][n], 0, 0, 0);
            }
    }
    // ---- rowsum reduce
    __syncthreads();
    rsred[ar][acs] = rs;
    __syncthreads();
    if (tid < 32) {
        float s = 0.f;
#pragma unroll
        for (int j = 0; j < 8; ++j) s += rsred[tid][j];
        rowsum[i0 + tid] = s;
    }
    // ---- C write (verified layout: col=lane&15, row=(lane>>4)*4+reg)
#pragma unroll
    for (int m = 0; m < 2; ++m)
#pragma unroll
        for (int n = 0; n < 4; ++n) {
            int orow = i0 + m * 16 + ((l >> 4) << 2);
            int ocol = (w << 6) + (n << 4) + lr;
            float* op = out + (size_t)orow * D + ocol;
#pragma unroll
            for (int v = 0; v < 4; ++v) op[(size_t)v * D] = acc[m][n][v];
        }
}

// K7: per-row epilogue: divide, elu, proj, logmap0, sigmoid, expmap0 (in-place on out)
__global__ void k_final(float* __restrict__ out, const float* __restrict__ rowsum) {
    __shared__ float sb[4];
    int row = blockIdx.x, t = threadIdx.x;
    float raw = out[(size_t)row * D + t];
    float rs = rowsum[row];
    float hp = raw / rs;
    float ey = 0.f;
    if (t >= 1) ey = (hp > 0.f) ? hp : expm1f(hp);
    float ss = breduce_sum256(ey * ey, sb);
    float x0 = sqrtf(1.f + ss);
    float th = fmaxf(x0, 1.f + 1e-7f);
    float al = acoshf(th);
    float yn = fmaxf(sqrtf(ss), 1e-15f);
    float u = (t >= 1) ? (al * ey / yn) : 0.f;
    float s = 1.f / (1.f + expf(-u));
    float s2 = (t >= 1) ? s * s : 0.f;
    float ssn = breduce_sum256(s2, sb);
    float xn = fmaxf(sqrtf(ssn), 1e-15f);
    float sh = sinhf(xn);
    float yf = (t >= 1) ? (sh * s / xn) : 0.f;
    float sy = breduce_sum256(yf * yf, sb);
    float res = (t == 0) ? sqrtf(1.f + sy) : yf;
    out[(size_t)row * D + t] = res;
}

extern "C" void kernel_launch(void* const* d_in, const int* in_sizes, int n_in,
                              void* d_out, int out_size, void* d_ws, size_t ws_size,
                              hipStream_t stream) {
    const float* x    = (const float*)d_in[0];
    const int*   adj  = (const int*)d_in[1];
    const float* Wg   = (const float*)d_in[3];
    const float* Wa   = (const float*)d_in[4];
    const float* aatt = (const float*)d_in[5];
    float* out = (float*)d_out;

    char* wsb = (char*)d_ws;
    float*          M2     = (float*)(wsb);                  // 261,120 B
    float*          h      = (float*)(wsb + 0x040000);       // 8 MB
    unsigned short* GT     = (unsigned short*)(wsb + 0x840000); // 4 MB
    float*          cvec   = (float*)(wsb + 0xC40000);       // 32 KB
    float*          wexp   = (float*)(wsb + 0xC48000);       // 32 KB
    float*          rowsum = (float*)(wsb + 0xC50000);       // 32 KB
    float*          Mval   = (float*)(wsb + 0xC58000);       // 4 B

    k_logmap0<<<N_ROWS, 256, 0, stream>>>(x, out);           // L in d_out
    k_M2<<<255, 256, 0, stream>>>(Wg, Wa, M2);
    k_h<<<N_ROWS / 8, 256, 0, stream>>>(out, M2, h);
    k_cvec<<<N_ROWS, 256, 0, stream>>>(h, aatt, cvec);
    k_max<<<1, 256, 0, stream>>>(cvec, Mval);
    k_wexp<<<N_ROWS / 256, 256, 0, stream>>>(cvec, Mval, wexp);
    k_makeGT<<<dim3(N_ROWS / 64, 4), 256, 0, stream>>>(h, wexp, GT);
    k_attgemm<<<N_ROWS / 32, 256, 0, stream>>>(adj, GT, wexp, out, rowsum);
    k_final<<<N_ROWS, 256, 0, stream>>>(out, rowsum);
}